// Round 7
// baseline (1616.394 us; speedup 1.0000x reference)
//
#include <hip/hip_runtime.h>
#include <hip/hip_bf16.h>
#include <stdint.h>

#define NN 4096
#define DD 256
#define NL 3
typedef unsigned int uint;
typedef unsigned short ushort_t;

typedef float f32x4 __attribute__((ext_vector_type(4)));
typedef short bf16x8 __attribute__((ext_vector_type(8)));

struct Ptrs4 { const float* p0; const float* p1; const float* p2; const float* p3; };
__device__ __forceinline__ const float* sel(const Ptrs4& p, int b) {
    return b == 0 ? p.p0 : b == 1 ? p.p1 : b == 2 ? p.p2 : p.p3;
}

// packed bf16 pair (RNE), low half = a, high half = b
__device__ __forceinline__ uint pkbf2(float a, float b) {
    __hip_bfloat162 t = __float22bfloat162_rn(float2{a, b});
    union { __hip_bfloat162 h; uint u; } c; c.h = t; return c.u;
}
// exact 3-way split of a pair: x = h + m + l + r, |r| <= ~2^-27 |x|
__device__ __forceinline__ void split3_pk(float a, float b, uint& h, uint& m, uint& l) {
    h = pkbf2(a, b);
    float ha = __uint_as_float(h << 16), hb = __uint_as_float(h & 0xFFFF0000u);
    float ra = a - ha, rb = b - hb;
    m = pkbf2(ra, rb);
    float ma = __uint_as_float(m << 16), mb = __uint_as_float(m & 0xFFFF0000u);
    l = pkbf2(ra - ma, rb - mb);
}

// ---------------------------------------------------------------------------
// fp32 GEMM (proven): Out = act(X @ W + b).
// MODE 0: elu; MODE 1: elu + colsum; MODE 2: linear + BN stats.
// ---------------------------------------------------------------------------
template<int MODE>
__global__ __launch_bounds__(256, 2)
void gemm_small(const float* __restrict__ Xin, Ptrs4 Wp, Ptrs4 bp,
                float* __restrict__ Out, float* __restrict__ cs, float* __restrict__ csq)
{
    const int b = blockIdx.z;
    const float* Wb = sel(Wp, b);
    const float* bb = sel(bp, b);
    const float* X = Xin + (size_t)b * NN * DD;
    float* O = Out + (size_t)b * NN * DD;
    const int row0 = blockIdx.y * 128, col0 = blockIdx.x * 64;
    const int tid = threadIdx.x;
    __shared__ float Asm[16][132];
    __shared__ float Bsm[16][68];
    const int tr = (tid >> 4) << 3, tc = (tid & 15) << 2;
    const int m = tid & 127, kk = (tid >> 7) << 3;
    float acc[8][4] = {};
    for (int k0 = 0; k0 < DD; k0 += 16) {
        {
            const float* s1 = X + (size_t)(row0 + m) * DD + k0 + kk;
            float4 v0 = *(const float4*)s1, v1 = *(const float4*)(s1 + 4);
            Asm[kk+0][m]=v0.x; Asm[kk+1][m]=v0.y; Asm[kk+2][m]=v0.z; Asm[kk+3][m]=v0.w;
            Asm[kk+4][m]=v1.x; Asm[kk+5][m]=v1.y; Asm[kk+6][m]=v1.z; Asm[kk+7][m]=v1.w;
        }
        {
            const int k = tid >> 4, n = (tid & 15) << 2;
            *(float4*)&Bsm[k][n] = *(const float4*)(Wb + (size_t)(k0 + k) * DD + col0 + n);
        }
        __syncthreads();
        #pragma unroll
        for (int k = 0; k < 16; ++k) {
            float a[8], bv[4];
            *(float4*)&a[0] = *(const float4*)&Asm[k][tr];
            *(float4*)&a[4] = *(const float4*)&Asm[k][tr + 4];
            *(float4*)&bv[0] = *(const float4*)&Bsm[k][tc];
            #pragma unroll
            for (int i = 0; i < 8; ++i)
                #pragma unroll
                for (int j = 0; j < 4; ++j)
                    acc[i][j] = fmaf(a[i], bv[j], acc[i][j]);
        }
        __syncthreads();
    }
    float bias4[4];
    *(float4*)bias4 = *(const float4*)(bb + col0 + tc);
    float s4[4] = {0.f,0.f,0.f,0.f}, q4[4] = {0.f,0.f,0.f,0.f};
    #pragma unroll
    for (int i = 0; i < 8; ++i) {
        float ov[4];
        #pragma unroll
        for (int j = 0; j < 4; ++j) {
            float v = acc[i][j] + bias4[j];
            if (MODE == 0 || MODE == 1) v = (v > 0.f) ? v : (expf(v) - 1.f);
            ov[j] = v;
            if (MODE == 1) s4[j] += v;
            if (MODE == 2) { s4[j] += v; q4[j] += v * v; }
        }
        float4 o; o.x = ov[0]; o.y = ov[1]; o.z = ov[2]; o.w = ov[3];
        *(float4*)(O + (size_t)(row0 + tr + i) * DD + col0 + tc) = o;
    }
    if (MODE == 1 || MODE == 2) {
        __syncthreads();
        const int rg = tid >> 4;
        #pragma unroll
        for (int j = 0; j < 4; ++j) {
            Asm[rg][tc + j] = s4[j];
            if (MODE == 2) Bsm[rg][tc + j] = q4[j];
        }
        __syncthreads();
        if (tid < 64) {
            float s = 0.f, q = 0.f;
            #pragma unroll
            for (int r = 0; r < 16; ++r) { s += Asm[r][tid]; if (MODE == 2) q += Bsm[r][tid]; }
            atomicAdd(&cs[b * DD + col0 + tid], s);
            if (MODE == 2) atomicAdd(&csq[b * DD + col0 + tid], q);
        }
    }
}

// threshold per branch: t = ||colsum||^2 / N^2
__global__ void thresh_k(const float* __restrict__ cs, float* __restrict__ tvals)
{
    const int b = blockIdx.x, t = threadIdx.x;
    __shared__ float red[256];
    float v = cs[b * DD + t];
    red[t] = v * v;
    __syncthreads();
    for (int s = 128; s > 0; s >>= 1) { if (t < s) red[t] += red[t + s]; __syncthreads(); }
    if (t == 0) tvals[b] = red[0] * (1.0f / 16777216.0f);
}

// ---------------------------------------------------------------------------
// transpose + exact 3-split: X[b][n][d] fp32 -> S{h,m,l}[b][d][j=n] bf16.
// j-contiguous layout = MFMA k-order for masked_mfma's B operand.  (proven)
// ---------------------------------------------------------------------------
__global__ __launch_bounds__(256)
void tsplit_x(const float* __restrict__ Xin, ushort_t* __restrict__ Sh,
              ushort_t* __restrict__ Sm, ushort_t* __restrict__ Sl)
{
    const int b = blockIdx.z;
    const int n0 = blockIdx.x * 64, d0 = blockIdx.y * 64;
    const float* X = Xin + (size_t)b * NN * DD;
    __shared__ float ls[64][65];
    const int tid = threadIdx.x;
    #pragma unroll
    for (int i = 0; i < 4; ++i) {
        int u = (i << 8) + tid;
        int r = u >> 4, c4 = (u & 15) << 2;   // r = n-row, c4 = d offset
        float4 v = *(const float4*)(X + (size_t)(n0 + r) * DD + d0 + c4);
        ls[r][c4] = v.x; ls[r][c4+1] = v.y; ls[r][c4+2] = v.z; ls[r][c4+3] = v.w;
    }
    __syncthreads();
    const int d = tid >> 2, seg = (tid & 3) << 4;   // 16 n-values per thread
    uint ph[8], pm[8], pl[8];
    #pragma unroll
    for (int jj = 0; jj < 8; ++jj) {
        float a = ls[seg + 2 * jj][d];
        float c = ls[seg + 2 * jj + 1][d];
        split3_pk(a, c, ph[jj], pm[jj], pl[jj]);
    }
    size_t idx = ((size_t)(b * DD + d0 + d)) * NN + n0 + seg;   // ushort units
    *(uint4*)(Sh + idx)     = *(uint4*)&ph[0];
    *(uint4*)(Sh + idx + 8) = *(uint4*)&ph[4];
    *(uint4*)(Sm + idx)     = *(uint4*)&pm[0];
    *(uint4*)(Sm + idx + 8) = *(uint4*)&pm[4];
    *(uint4*)(Sl + idx)     = *(uint4*)&pl[0];
    *(uint4*)(Sl + idx + 8) = *(uint4*)&pl[4];
}

// ---------------------------------------------------------------------------
// adj via MFMA, symmetric-halved: only bx>=by tiles computed; mirror tile's
// mask bits assembled from the same accumulators (bitwise-identical dot).
// Split done once per LDS tile during staging. 6 products; bits via ballot.
// ---------------------------------------------------------------------------
__global__ __launch_bounds__(256, 2)
void adj_mfma_s(const float* __restrict__ H, const float* __restrict__ tvals,
                uint8_t* __restrict__ mask)
{
    const int bx = blockIdx.x, by = blockIdx.y, b = blockIdx.z;
    if (bx < by) return;
    const int row0 = by * 128, col0 = bx * 128;
    const int tid = threadIdx.x;
    const int wave = tid >> 6, ln = tid & 15, quad = (tid >> 4) & 3;
    const int wrow = wave >> 1, wcol = wave & 1;
    const float* Hb = H + (size_t)b * NN * DD;
    uint8_t* Mb = mask + (size_t)b * NN * (NN / 8);
    __shared__ ushort_t hs[2][3][128][36];   // [side][lvl][row][32k+pad], 55.3 KB

    f32x4 acc[4][4] = {};
    for (int k0 = 0; k0 < DD; k0 += 32) {
        #pragma unroll
        for (int i = 0; i < 8; ++i) {
            int f = (i << 8) + tid;
            int sr = f >> 3;                 // (side,row)
            int side = sr >> 7, r = sr & 127, part = f & 7;   // part = 4-k group
            int grow = (side ? col0 : row0) + r;
            float4 v = *(const float4*)(Hb + (size_t)grow * DD + k0 + part * 4);
            uint h0, m0, l0, h1, m1, l1;
            split3_pk(v.x, v.y, h0, m0, l0);
            split3_pk(v.z, v.w, h1, m1, l1);
            uint2 ph; ph.x = h0; ph.y = h1;
            uint2 pm; pm.x = m0; pm.y = m1;
            uint2 pl; pl.x = l0; pl.y = l1;
            *(uint2*)&hs[side][0][r][part * 4] = ph;
            *(uint2*)&hs[side][1][r][part * 4] = pm;
            *(uint2*)&hs[side][2][r][part * 4] = pl;
        }
        __syncthreads();
        bf16x8 af[4][3];
        #pragma unroll
        for (int mt = 0; mt < 4; ++mt)
            #pragma unroll
            for (int lvl = 0; lvl < 3; ++lvl)
                af[mt][lvl] = *(const bf16x8*)&hs[0][lvl][wrow * 64 + mt * 16 + ln][quad * 8];
        #pragma unroll
        for (int nt = 0; nt < 4; ++nt) {
            int n = wcol * 64 + nt * 16 + ln;
            bf16x8 bh = *(const bf16x8*)&hs[1][0][n][quad * 8];
            bf16x8 bm = *(const bf16x8*)&hs[1][1][n][quad * 8];
            bf16x8 bl = *(const bf16x8*)&hs[1][2][n][quad * 8];
            #pragma unroll
            for (int mt = 0; mt < 4; ++mt) {
                f32x4 a = acc[mt][nt];
                a = __builtin_amdgcn_mfma_f32_16x16x32_bf16(af[mt][0], bh, a, 0, 0, 0);
                a = __builtin_amdgcn_mfma_f32_16x16x32_bf16(af[mt][0], bm, a, 0, 0, 0);
                a = __builtin_amdgcn_mfma_f32_16x16x32_bf16(af[mt][1], bh, a, 0, 0, 0);
                a = __builtin_amdgcn_mfma_f32_16x16x32_bf16(af[mt][0], bl, a, 0, 0, 0);
                a = __builtin_amdgcn_mfma_f32_16x16x32_bf16(af[mt][2], bh, a, 0, 0, 0);
                a = __builtin_amdgcn_mfma_f32_16x16x32_bf16(af[mt][1], bm, a, 0, 0, 0);
                acc[mt][nt] = a;
            }
        }
        __syncthreads();
    }
    const float t = tvals[b];
    #pragma unroll
    for (int mt = 0; mt < 4; ++mt)
        #pragma unroll
        for (int nt = 0; nt < 4; ++nt) {
            bool p0 = acc[mt][nt][0] > t, p1 = acc[mt][nt][1] > t;
            bool p2 = acc[mt][nt][2] > t, p3 = acc[mt][nt][3] > t;
            // --- normal tile: bits across lanes (cols) via ballot ---
            unsigned long long bal[4];
            bal[0] = __ballot(p0); bal[1] = __ballot(p1);
            bal[2] = __ballot(p2); bal[3] = __ballot(p3);
            if ((tid & 63) < 16) {
                int q = ln >> 2, rsel = ln & 3;
                unsigned long long bv = rsel == 0 ? bal[0] : rsel == 1 ? bal[1]
                                       : rsel == 2 ? bal[2] : bal[3];
                ushort_t u16 = (ushort_t)((bv >> (q * 16)) & 0xFFFFull);
                int row = row0 + wrow * 64 + mt * 16 + ln;
                int colb = (col0 + wcol * 64 + nt * 16) >> 3;
                *(ushort_t*)(Mb + (size_t)row * (NN / 8) + colb) = u16;
            }
            // --- mirror tile: bits across rows, assembled from quad pairs ---
            uint nib = (p0 ? 1u : 0u) | (p1 ? 2u : 0u) | (p2 ? 4u : 0u) | (p3 ? 8u : 0u);
            uint other = (uint)__shfl_xor((int)nib, 16);   // partner quad (q^1)
            if ((quad & 1) == 0) {
                uint byt = nib | (other << 4);
                int rowm = col0 + wcol * 64 + nt * 16 + ln;
                int colbm = ((row0 + wrow * 64 + mt * 16) >> 3) + (quad >> 1);
                Mb[(size_t)rowm * (NN / 8) + colbm] = (uint8_t)byt;
            }
        }
}

// ---------------------------------------------------------------------------
// X' = X + M @ X via MFMA, IN-PLACE into X. A = mask bits -> exact {0,1}
// bf16; B staged from precomputed global bf16 splits [lvl][d][j].  (proven)
// ---------------------------------------------------------------------------
__global__ __launch_bounds__(256, 3)
void masked_mfma(float* __restrict__ Xio, const ushort_t* __restrict__ Sh,
                 const ushort_t* __restrict__ Sm, const ushort_t* __restrict__ Sl,
                 const uint8_t* __restrict__ mask)
{
    const int b = blockIdx.z;
    const int row0 = blockIdx.y * 128, col0 = blockIdx.x * 64;
    const int tid = threadIdx.x;
    const int wave = tid >> 6, ln = tid & 15, quad = (tid >> 4) & 3;
    const int wrow = wave >> 1, wcol = wave & 1;
    float* X = Xio + (size_t)b * NN * DD;
    const size_t sb = (size_t)b * DD * NN;
    const ushort_t* Ss[3] = { Sh + sb, Sm + sb, Sl + sb };
    const uint* Mw = (const uint*)(mask + (size_t)b * NN * (NN / 8));
    __shared__ ushort_t bt[3][64][40];   // [lvl][col][32 j + pad], 15.4 KB
    __shared__ uint msk[128];

    f32x4 acc[4][2] = {};
    const int scol = tid >> 2, spart = tid & 3;
    for (int j0 = 0; j0 < NN; j0 += 32) {
        #pragma unroll
        for (int lvl = 0; lvl < 3; ++lvl) {
            uint4 v = *(const uint4*)(Ss[lvl] + (size_t)(col0 + scol) * NN + j0 + spart * 8);
            *(uint4*)&bt[lvl][scol][spart * 8] = v;
        }
        if (tid < 128) msk[tid] = Mw[(size_t)(row0 + tid) * 128 + (j0 >> 5)];
        __syncthreads();
        bf16x8 afr[4];
        #pragma unroll
        for (int mt = 0; mt < 4; ++mt) {
            uint w = msk[wrow * 64 + mt * 16 + ln];
            uint byte = (w >> (quad * 8)) & 0xFFu;
            union { uint u[4]; bf16x8 v; } cv;
            #pragma unroll
            for (int p = 0; p < 4; ++p)
                cv.u[p] = (((byte >> (2 * p)) & 1u) ? 0x3F80u : 0u) |
                          (((byte >> (2 * p + 1)) & 1u) ? 0x3F800000u : 0u);
            afr[mt] = cv.v;
        }
        #pragma unroll
        for (int nt = 0; nt < 2; ++nt) {
            int n = wcol * 32 + nt * 16 + ln;
            bf16x8 bh = *(const bf16x8*)&bt[0][n][quad * 8];
            bf16x8 bm = *(const bf16x8*)&bt[1][n][quad * 8];
            bf16x8 bl = *(const bf16x8*)&bt[2][n][quad * 8];
            #pragma unroll
            for (int mt = 0; mt < 4; ++mt) {
                f32x4 a = acc[mt][nt];
                a = __builtin_amdgcn_mfma_f32_16x16x32_bf16(afr[mt], bh, a, 0, 0, 0);
                a = __builtin_amdgcn_mfma_f32_16x16x32_bf16(afr[mt], bm, a, 0, 0, 0);
                a = __builtin_amdgcn_mfma_f32_16x16x32_bf16(afr[mt], bl, a, 0, 0, 0);
                acc[mt][nt] = a;
            }
        }
        __syncthreads();
    }
    #pragma unroll
    for (int mt = 0; mt < 4; ++mt)
        #pragma unroll
        for (int nt = 0; nt < 2; ++nt)
            #pragma unroll
            for (int r = 0; r < 4; ++r) {
                int row = row0 + wrow * 64 + mt * 16 + quad * 4 + r;
                int col = col0 + wcol * 32 + nt * 16 + ln;
                size_t idx = (size_t)row * DD + col;
                X[idx] = X[idx] + acc[mt][nt][r];   // in-place: each idx owned by one thread
            }
}

// ---------------------------------------------------------------------------
// X = relu(bn(G)) @ W + bias;  acc (+)= X.  (proven)
// ---------------------------------------------------------------------------
__global__ __launch_bounds__(256, 2)
void gemm_bnrelu(const float* __restrict__ G, Ptrs4 Wp, Ptrs4 bp, Ptrs4 gbp,
                 const float* __restrict__ bns, const float* __restrict__ bnq,
                 float* __restrict__ Xout, float* __restrict__ accb, int first)
{
    const int b = blockIdx.z;
    const float* Wb = sel(Wp, b);
    const float* bb = sel(bp, b);
    const float* gb = sel(gbp, b);
    const float* Gb = G + (size_t)b * NN * DD;
    float* O = Xout + (size_t)b * NN * DD;
    float* Ab = accb + (size_t)b * NN * DD;
    const int row0 = blockIdx.y * 128, col0 = blockIdx.x * 64;
    const int tid = threadIdx.x;
    __shared__ float Asm[16][132];
    __shared__ float Bsm[16][68];
    __shared__ float scs[DD], shs[DD];
    {
        float mu = bns[b * DD + tid] * (1.0f / NN);
        float ms = bnq[b * DD + tid] * (1.0f / NN);
        float var = ms - mu * mu;
        float sc = gb[tid] / sqrtf(var + 1e-5f);
        scs[tid] = sc;
        shs[tid] = gb[DD + tid] - mu * sc;
    }
    __syncthreads();
    const int tr = (tid >> 4) << 3, tc = (tid & 15) << 2;
    const int m = tid & 127, kk = (tid >> 7) << 3;
    float acc[8][4] = {};
    for (int k0 = 0; k0 < DD; k0 += 16) {
        {
            const float* s1 = Gb + (size_t)(row0 + m) * DD + k0 + kk;
            float4 v0 = *(const float4*)s1, v1 = *(const float4*)(s1 + 4);
            float vv[8] = {v0.x, v0.y, v0.z, v0.w, v1.x, v1.y, v1.z, v1.w};
            #pragma unroll
            for (int i = 0; i < 8; ++i) {
                float v = fmaf(vv[i], scs[k0 + kk + i], shs[k0 + kk + i]);
                Asm[kk + i][m] = v > 0.f ? v : 0.f;
            }
        }
        {
            const int k = tid >> 4, n = (tid & 15) << 2;
            *(float4*)&Bsm[k][n] = *(const float4*)(Wb + (size_t)(k0 + k) * DD + col0 + n);
        }
        __syncthreads();
        #pragma unroll
        for (int k = 0; k < 16; ++k) {
            float a[8], bv[4];
            *(float4*)&a[0] = *(const float4*)&Asm[k][tr];
            *(float4*)&a[4] = *(const float4*)&Asm[k][tr + 4];
            *(float4*)&bv[0] = *(const float4*)&Bsm[k][tc];
            #pragma unroll
            for (int i = 0; i < 8; ++i)
                #pragma unroll
                for (int j = 0; j < 4; ++j)
                    acc[i][j] = fmaf(a[i], bv[j], acc[i][j]);
        }
        __syncthreads();
    }
    float bias4[4];
    *(float4*)bias4 = *(const float4*)(bb + col0 + tc);
    #pragma unroll
    for (int i = 0; i < 8; ++i) {
        size_t idx = (size_t)(row0 + tr + i) * DD + col0 + tc;
        float4 o;
        o.x = acc[i][0] + bias4[0]; o.y = acc[i][1] + bias4[1];
        o.z = acc[i][2] + bias4[2]; o.w = acc[i][3] + bias4[3];
        *(float4*)(O + idx) = o;
        if (first) {
            *(float4*)(Ab + idx) = o;
        } else {
            float4 p = *(const float4*)(Ab + idx);
            p.x += o.x; p.y += o.y; p.z += o.z; p.w += o.w;
            *(float4*)(Ab + idx) = p;
        }
    }
}

__global__ __launch_bounds__(256)
void mse_partial(const float* __restrict__ accb, double* __restrict__ msep)
{
    const int pair = blockIdx.x;
    const float* A_ = accb + (size_t)pair * NN * DD;
    const float* B_ = accb + (size_t)3 * NN * DD;
    const size_t total = (size_t)NN * DD;
    double s = 0.0;
    for (size_t i = (size_t)blockIdx.y * blockDim.x + threadIdx.x; i < total;
         i += (size_t)gridDim.y * blockDim.x) {
        float d = A_[i] - B_[i];
        s += (double)d * (double)d;
    }
    __shared__ double red[256];
    red[threadIdx.x] = s;
    __syncthreads();
    for (int st = 128; st > 0; st >>= 1) {
        if (threadIdx.x < st) red[threadIdx.x] += red[threadIdx.x + st];
        __syncthreads();
    }
    if (threadIdx.x == 0) atomicAdd(&msep[pair], red[0]);
}

__global__ void mse_final(const double* __restrict__ msep, float* __restrict__ out)
{
    int i = threadIdx.x;
    if (i < 3) out[i] = (float)(msep[i] / ((double)NN * DD) / 9.0);
}

static inline Ptrs4 mk4(const float* a, const float* b, const float* c, const float* d) {
    Ptrs4 p; p.p0 = a; p.p1 = b; p.p2 = c; p.p3 = d; return p;
}

extern "C" void kernel_launch(void* const* d_in, const int* in_sizes, int n_in,
                              void* d_out, int out_size, void* d_ws, size_t ws_size,
                              hipStream_t stream)
{
    (void)in_sizes; (void)n_in; (void)out_size; (void)ws_size;
    const float* adjW[3]  = {(const float*)d_in[4],  (const float*)d_in[9],  (const float*)d_in[14]};
    const float* adjb[3]  = {(const float*)d_in[5],  (const float*)d_in[10], (const float*)d_in[15]};
    const float* mlpW[3]  = {(const float*)d_in[6],  (const float*)d_in[11], (const float*)d_in[16]};
    const float* mlpb[3]  = {(const float*)d_in[7],  (const float*)d_in[12], (const float*)d_in[17]};
    const float* mlpbn[3] = {(const float*)d_in[8],  (const float*)d_in[13], (const float*)d_in[18]};

    // Workspace layout: identical proven footprint (~75 MB).
    char* ws = (char*)d_ws;
    double* msep  = (double*)ws;                 // [3]
    float* colsum = (float*)(ws + 64);           // [3][4][256]
    float* bnsum  = colsum + 3 * 4 * DD;
    float* bnsq   = bnsum  + 3 * 4 * DD;
    float* tvals  = bnsq   + 3 * 4 * DD;         // [4]
    const size_t tensN = (size_t)4 * NN * DD;
    float* Xbuf = (float*)(ws + 65536);
    float* Abuf = Xbuf + tensN;                  // h1 -> {Sh,Sm} -> g
    float* Bbuf = Abuf + tensN;                  // h2 -> {Sl}
    float* accb = Bbuf + tensN;
    uint8_t* mask = (uint8_t*)(accb + tensN);    // [4][N][N/8] = 8 MB
    // bf16 split views (time-multiplexed over Abuf/Bbuf)
    ushort_t* Sh = (ushort_t*)Abuf;              // [4][D][N] = 8.4 MB
    ushort_t* Sm = Sh + tensN;                   // second half of Abuf
    ushort_t* Sl = (ushort_t*)Bbuf;              // first half of Bbuf

    hipMemsetAsync(ws, 0, 64 + 3 * 3 * 4 * DD * sizeof(float), stream);
    for (int b = 0; b < 4; ++b)
        hipMemcpyAsync(Xbuf + (size_t)b * NN * DD, d_in[b], (size_t)NN * DD * sizeof(float),
                       hipMemcpyDeviceToDevice, stream);

    dim3 gS(4, 32, 4);      // fp32 GEMMs / masked_mfma
    dim3 gA(32, 32, 4);     // adj tiles (upper-tri active)
    dim3 gT(64, 4, 4);      // tsplit_x
    dim3 blk(256);

    for (int l = 0; l < NL; ++l) {
        float* cs_l = colsum + l * 4 * DD;
        float* bs_l = bnsum + l * 4 * DD;
        float* bq_l = bnsq  + l * 4 * DD;
        #define MK(arr, off) mk4(arr[0] + (off), arr[1] + (off), arr[2] + (off), arr[1] + (off))
        // h1 = elu(X @ aW0 + ab0)  -> Abuf
        gemm_small<0><<<gS, blk, 0, stream>>>(Xbuf, MK(adjW, 0), MK(adjb, 0), Abuf, nullptr, nullptr);
        // h2 = elu(h1 @ aW1 + ab1) + colsum  -> Bbuf
        gemm_small<1><<<gS, blk, 0, stream>>>(Abuf, MK(adjW, (size_t)DD * DD), MK(adjb, DD),
                                              Bbuf, cs_l, nullptr);
        thresh_k<<<4, blk, 0, stream>>>(cs_l, tvals);
        // mask = (h2 h2^T > mean), symmetric-halved
        adj_mfma_s<<<gA, blk, 0, stream>>>(Bbuf, tvals, mask);
        // splits of X^T (h1, h2 dead) -> Sh,Sm (Abuf), Sl (Bbuf)
        tsplit_x<<<gT, blk, 0, stream>>>(Xbuf, Sh, Sm, Sl);
        // X = X + M @ X   (in-place Xbuf)
        masked_mfma<<<gS, blk, 0, stream>>>(Xbuf, Sh, Sm, Sl, mask);
        const size_t w0 = (size_t)l * 2 * DD * DD, b0 = (size_t)l * 2 * DD;
        // g = X' @ mW0 + mb0 + BN stats  -> Abuf (splits dead)
        gemm_small<2><<<gS, blk, 0, stream>>>(Xbuf, MK(mlpW, w0), MK(mlpb, b0), Abuf, bs_l, bq_l);
        // X = relu(bn(g)) @ mW1 + mb1;  acc (+)= X  -> Xbuf
        gemm_bnrelu<<<gS, blk, 0, stream>>>(Abuf, MK(mlpW, w0 + (size_t)DD * DD), MK(mlpb, b0 + DD),
                                            MK(mlpbn, b0), bs_l, bq_l, Xbuf, accb, (l == 0) ? 1 : 0);
        #undef MK
    }
    mse_partial<<<dim3(3, 64), blk, 0, stream>>>(accb, msep);
    mse_final<<<1, 64, 0, stream>>>(msep, (float*)d_out);
}

// Round 8
// 1437.845 us; speedup vs baseline: 1.1242x; 1.1242x over previous
//
#include <hip/hip_runtime.h>
#include <hip/hip_bf16.h>
#include <stdint.h>

#define NN 4096
#define DD 256
#define NL 3
typedef unsigned int uint;
typedef unsigned short ushort_t;

typedef float f32x4 __attribute__((ext_vector_type(4)));
typedef short bf16x8 __attribute__((ext_vector_type(8)));

struct Ptrs4 { const float* p0; const float* p1; const float* p2; const float* p3; };
__device__ __forceinline__ const float* sel(const Ptrs4& p, int b) {
    return b == 0 ? p.p0 : b == 1 ? p.p1 : b == 2 ? p.p2 : p.p3;
}

// packed bf16 pair (RNE), low half = a, high half = b
__device__ __forceinline__ uint pkbf2(float a, float b) {
    __hip_bfloat162 t = __float22bfloat162_rn(float2{a, b});
    union { __hip_bfloat162 h; uint u; } c; c.h = t; return c.u;
}
// exact 3-way split of a pair: x = h + m + l + r, |r| <= ~2^-27 |x|
__device__ __forceinline__ void split3_pk(float a, float b, uint& h, uint& m, uint& l) {
    h = pkbf2(a, b);
    float ha = __uint_as_float(h << 16), hb = __uint_as_float(h & 0xFFFF0000u);
    float ra = a - ha, rb = b - hb;
    m = pkbf2(ra, rb);
    float ma = __uint_as_float(m << 16), mb = __uint_as_float(m & 0xFFFF0000u);
    l = pkbf2(ra - ma, rb - mb);
}

// ---------------------------------------------------------------------------
// fp32 GEMM (proven): Out = act(X @ W + b).
// MODE 0: elu; MODE 1: elu + colsum; MODE 2: linear + BN stats.
// ---------------------------------------------------------------------------
template<int MODE>
__global__ __launch_bounds__(256, 2)
void gemm_small(const float* __restrict__ Xin, Ptrs4 Wp, Ptrs4 bp,
                float* __restrict__ Out, float* __restrict__ cs, float* __restrict__ csq)
{
    const int b = blockIdx.z;
    const float* Wb = sel(Wp, b);
    const float* bb = sel(bp, b);
    const float* X = Xin + (size_t)b * NN * DD;
    float* O = Out + (size_t)b * NN * DD;
    const int row0 = blockIdx.y * 128, col0 = blockIdx.x * 64;
    const int tid = threadIdx.x;
    __shared__ float Asm[16][132];
    __shared__ float Bsm[16][68];
    const int tr = (tid >> 4) << 3, tc = (tid & 15) << 2;
    const int m = tid & 127, kk = (tid >> 7) << 3;
    float acc[8][4] = {};
    for (int k0 = 0; k0 < DD; k0 += 16) {
        {
            const float* s1 = X + (size_t)(row0 + m) * DD + k0 + kk;
            float4 v0 = *(const float4*)s1, v1 = *(const float4*)(s1 + 4);
            Asm[kk+0][m]=v0.x; Asm[kk+1][m]=v0.y; Asm[kk+2][m]=v0.z; Asm[kk+3][m]=v0.w;
            Asm[kk+4][m]=v1.x; Asm[kk+5][m]=v1.y; Asm[kk+6][m]=v1.z; Asm[kk+7][m]=v1.w;
        }
        {
            const int k = tid >> 4, n = (tid & 15) << 2;
            *(float4*)&Bsm[k][n] = *(const float4*)(Wb + (size_t)(k0 + k) * DD + col0 + n);
        }
        __syncthreads();
        #pragma unroll
        for (int k = 0; k < 16; ++k) {
            float a[8], bv[4];
            *(float4*)&a[0] = *(const float4*)&Asm[k][tr];
            *(float4*)&a[4] = *(const float4*)&Asm[k][tr + 4];
            *(float4*)&bv[0] = *(const float4*)&Bsm[k][tc];
            #pragma unroll
            for (int i = 0; i < 8; ++i)
                #pragma unroll
                for (int j = 0; j < 4; ++j)
                    acc[i][j] = fmaf(a[i], bv[j], acc[i][j]);
        }
        __syncthreads();
    }
    float bias4[4];
    *(float4*)bias4 = *(const float4*)(bb + col0 + tc);
    float s4[4] = {0.f,0.f,0.f,0.f}, q4[4] = {0.f,0.f,0.f,0.f};
    #pragma unroll
    for (int i = 0; i < 8; ++i) {
        float ov[4];
        #pragma unroll
        for (int j = 0; j < 4; ++j) {
            float v = acc[i][j] + bias4[j];
            if (MODE == 0 || MODE == 1) v = (v > 0.f) ? v : (expf(v) - 1.f);
            ov[j] = v;
            if (MODE == 1) s4[j] += v;
            if (MODE == 2) { s4[j] += v; q4[j] += v * v; }
        }
        float4 o; o.x = ov[0]; o.y = ov[1]; o.z = ov[2]; o.w = ov[3];
        *(float4*)(O + (size_t)(row0 + tr + i) * DD + col0 + tc) = o;
    }
    if (MODE == 1 || MODE == 2) {
        __syncthreads();
        const int rg = tid >> 4;
        #pragma unroll
        for (int j = 0; j < 4; ++j) {
            Asm[rg][tc + j] = s4[j];
            if (MODE == 2) Bsm[rg][tc + j] = q4[j];
        }
        __syncthreads();
        if (tid < 64) {
            float s = 0.f, q = 0.f;
            #pragma unroll
            for (int r = 0; r < 16; ++r) { s += Asm[r][tid]; if (MODE == 2) q += Bsm[r][tid]; }
            atomicAdd(&cs[b * DD + col0 + tid], s);
            if (MODE == 2) atomicAdd(&csq[b * DD + col0 + tid], q);
        }
    }
}

// threshold per branch: t = ||colsum||^2 / N^2
__global__ void thresh_k(const float* __restrict__ cs, float* __restrict__ tvals)
{
    const int b = blockIdx.x, t = threadIdx.x;
    __shared__ float red[256];
    float v = cs[b * DD + t];
    red[t] = v * v;
    __syncthreads();
    for (int s = 128; s > 0; s >>= 1) { if (t < s) red[t] += red[t + s]; __syncthreads(); }
    if (t == 0) tvals[b] = red[0] * (1.0f / 16777216.0f);
}

// ---------------------------------------------------------------------------
// transpose + exact 3-split: X[b][n][d] fp32 -> S{h,m,l}[b][d][j=n] bf16.
// j-contiguous layout = MFMA k-order for masked_mfma's B operand.  (proven)
// ---------------------------------------------------------------------------
__global__ __launch_bounds__(256)
void tsplit_x(const float* __restrict__ Xin, ushort_t* __restrict__ Sh,
              ushort_t* __restrict__ Sm, ushort_t* __restrict__ Sl)
{
    const int b = blockIdx.z;
    const int n0 = blockIdx.x * 64, d0 = blockIdx.y * 64;
    const float* X = Xin + (size_t)b * NN * DD;
    __shared__ float ls[64][65];
    const int tid = threadIdx.x;
    #pragma unroll
    for (int i = 0; i < 4; ++i) {
        int u = (i << 8) + tid;
        int r = u >> 4, c4 = (u & 15) << 2;   // r = n-row, c4 = d offset
        float4 v = *(const float4*)(X + (size_t)(n0 + r) * DD + d0 + c4);
        ls[r][c4] = v.x; ls[r][c4+1] = v.y; ls[r][c4+2] = v.z; ls[r][c4+3] = v.w;
    }
    __syncthreads();
    const int d = tid >> 2, seg = (tid & 3) << 4;   // 16 n-values per thread
    uint ph[8], pm[8], pl[8];
    #pragma unroll
    for (int jj = 0; jj < 8; ++jj) {
        float a = ls[seg + 2 * jj][d];
        float c = ls[seg + 2 * jj + 1][d];
        split3_pk(a, c, ph[jj], pm[jj], pl[jj]);
    }
    size_t idx = ((size_t)(b * DD + d0 + d)) * NN + n0 + seg;   // ushort units
    *(uint4*)(Sh + idx)     = *(uint4*)&ph[0];
    *(uint4*)(Sh + idx + 8) = *(uint4*)&ph[4];
    *(uint4*)(Sm + idx)     = *(uint4*)&pm[0];
    *(uint4*)(Sm + idx + 8) = *(uint4*)&pm[4];
    *(uint4*)(Sl + idx)     = *(uint4*)&pl[0];
    *(uint4*)(Sl + idx + 8) = *(uint4*)&pl[4];
}

// ---------------------------------------------------------------------------
// adj via MFMA, symmetric-halved with COMPACT triangular grid (528 blocks
// per branch, no dead blocks) and 51 KB LDS -> 3 blocks/CU for latency
// hiding. Split once per LDS tile; 6 products; bits via ballot; mirror tile
// written from the same accumulators (bitwise-identical dot).
// ---------------------------------------------------------------------------
__global__ __launch_bounds__(256, 3)
void adj_mfma_s(const float* __restrict__ H, const float* __restrict__ tvals,
                uint8_t* __restrict__ mask)
{
    // decode linear triangular index -> (by, bx), bx >= by, row-major
    int t = blockIdx.x;
    int by = 0, rem = 32;
    while (t >= rem) { t -= rem; rem--; by++; }
    const int bx = by + t;
    const int b = blockIdx.z;
    const int row0 = by * 128, col0 = bx * 128;
    const int tid = threadIdx.x;
    const int wave = tid >> 6, ln = tid & 15, quad = (tid >> 4) & 3;
    const int wrow = wave >> 1, wcol = wave & 1;
    const float* Hb = H + (size_t)b * NN * DD;
    uint8_t* Mb = mask + (size_t)b * NN * (NN / 8);
    __shared__ ushort_t hs[2][3][128][34];   // [side][lvl][row][32k+pad], 51.0 KB

    f32x4 acc[4][4] = {};
    for (int k0 = 0; k0 < DD; k0 += 32) {
        #pragma unroll
        for (int i = 0; i < 8; ++i) {
            int f = (i << 8) + tid;
            int sr = f >> 3;                 // (side,row)
            int side = sr >> 7, r = sr & 127, part = f & 7;   // part = 4-k group
            int grow = (side ? col0 : row0) + r;
            float4 v = *(const float4*)(Hb + (size_t)grow * DD + k0 + part * 4);
            uint h0, m0, l0, h1, m1, l1;
            split3_pk(v.x, v.y, h0, m0, l0);
            split3_pk(v.z, v.w, h1, m1, l1);
            uint2 ph; ph.x = h0; ph.y = h1;
            uint2 pm; pm.x = m0; pm.y = m1;
            uint2 pl; pl.x = l0; pl.y = l1;
            *(uint2*)&hs[side][0][r][part * 4] = ph;
            *(uint2*)&hs[side][1][r][part * 4] = pm;
            *(uint2*)&hs[side][2][r][part * 4] = pl;
        }
        __syncthreads();
        bf16x8 af[4][3];
        #pragma unroll
        for (int mt = 0; mt < 4; ++mt)
            #pragma unroll
            for (int lvl = 0; lvl < 3; ++lvl)
                af[mt][lvl] = *(const bf16x8*)&hs[0][lvl][wrow * 64 + mt * 16 + ln][quad * 8];
        #pragma unroll
        for (int nt = 0; nt < 4; ++nt) {
            int n = wcol * 64 + nt * 16 + ln;
            bf16x8 bh = *(const bf16x8*)&hs[1][0][n][quad * 8];
            bf16x8 bm = *(const bf16x8*)&hs[1][1][n][quad * 8];
            bf16x8 bl = *(const bf16x8*)&hs[1][2][n][quad * 8];
            #pragma unroll
            for (int mt = 0; mt < 4; ++mt) {
                f32x4 a = acc[mt][nt];
                a = __builtin_amdgcn_mfma_f32_16x16x32_bf16(af[mt][0], bh, a, 0, 0, 0);
                a = __builtin_amdgcn_mfma_f32_16x16x32_bf16(af[mt][0], bm, a, 0, 0, 0);
                a = __builtin_amdgcn_mfma_f32_16x16x32_bf16(af[mt][1], bh, a, 0, 0, 0);
                a = __builtin_amdgcn_mfma_f32_16x16x32_bf16(af[mt][0], bl, a, 0, 0, 0);
                a = __builtin_amdgcn_mfma_f32_16x16x32_bf16(af[mt][2], bh, a, 0, 0, 0);
                a = __builtin_amdgcn_mfma_f32_16x16x32_bf16(af[mt][1], bm, a, 0, 0, 0);
                acc[mt][nt] = a;
            }
        }
        __syncthreads();
    }
    const float t2 = tvals[b];
    #pragma unroll
    for (int mt = 0; mt < 4; ++mt)
        #pragma unroll
        for (int nt = 0; nt < 4; ++nt) {
            bool p0 = acc[mt][nt][0] > t2, p1 = acc[mt][nt][1] > t2;
            bool p2 = acc[mt][nt][2] > t2, p3 = acc[mt][nt][3] > t2;
            // --- normal tile: bits across lanes (cols) via ballot ---
            unsigned long long bal[4];
            bal[0] = __ballot(p0); bal[1] = __ballot(p1);
            bal[2] = __ballot(p2); bal[3] = __ballot(p3);
            if ((tid & 63) < 16) {
                int q = ln >> 2, rsel = ln & 3;
                unsigned long long bv = rsel == 0 ? bal[0] : rsel == 1 ? bal[1]
                                       : rsel == 2 ? bal[2] : bal[3];
                ushort_t u16 = (ushort_t)((bv >> (q * 16)) & 0xFFFFull);
                int row = row0 + wrow * 64 + mt * 16 + ln;
                int colb = (col0 + wcol * 64 + nt * 16) >> 3;
                *(ushort_t*)(Mb + (size_t)row * (NN / 8) + colb) = u16;
            }
            // --- mirror tile: bits across rows, assembled from quad pairs ---
            uint nib = (p0 ? 1u : 0u) | (p1 ? 2u : 0u) | (p2 ? 4u : 0u) | (p3 ? 8u : 0u);
            uint other = (uint)__shfl_xor((int)nib, 16);   // partner quad (q^1)
            if ((quad & 1) == 0) {
                uint byt = nib | (other << 4);
                int rowm = col0 + wcol * 64 + nt * 16 + ln;
                int colbm = ((row0 + wrow * 64 + mt * 16) >> 3) + (quad >> 1);
                Mb[(size_t)rowm * (NN / 8) + colbm] = (uint8_t)byt;
            }
        }
}

// ---------------------------------------------------------------------------
// X' = X + M @ X via MFMA, IN-PLACE into X. A = mask bits -> exact {0,1}
// bf16; B staged from precomputed global bf16 splits [lvl][d][j].  (proven)
// ---------------------------------------------------------------------------
__global__ __launch_bounds__(256, 3)
void masked_mfma(float* __restrict__ Xio, const ushort_t* __restrict__ Sh,
                 const ushort_t* __restrict__ Sm, const ushort_t* __restrict__ Sl,
                 const uint8_t* __restrict__ mask)
{
    const int b = blockIdx.z;
    const int row0 = blockIdx.y * 128, col0 = blockIdx.x * 64;
    const int tid = threadIdx.x;
    const int wave = tid >> 6, ln = tid & 15, quad = (tid >> 4) & 3;
    const int wrow = wave >> 1, wcol = wave & 1;
    float* X = Xio + (size_t)b * NN * DD;
    const size_t sb = (size_t)b * DD * NN;
    const ushort_t* Ss[3] = { Sh + sb, Sm + sb, Sl + sb };
    const uint* Mw = (const uint*)(mask + (size_t)b * NN * (NN / 8));
    __shared__ ushort_t bt[3][64][40];   // [lvl][col][32 j + pad], 15.4 KB
    __shared__ uint msk[128];

    f32x4 acc[4][2] = {};
    const int scol = tid >> 2, spart = tid & 3;
    for (int j0 = 0; j0 < NN; j0 += 32) {
        #pragma unroll
        for (int lvl = 0; lvl < 3; ++lvl) {
            uint4 v = *(const uint4*)(Ss[lvl] + (size_t)(col0 + scol) * NN + j0 + spart * 8);
            *(uint4*)&bt[lvl][scol][spart * 8] = v;
        }
        if (tid < 128) msk[tid] = Mw[(size_t)(row0 + tid) * 128 + (j0 >> 5)];
        __syncthreads();
        bf16x8 afr[4];
        #pragma unroll
        for (int mt = 0; mt < 4; ++mt) {
            uint w = msk[wrow * 64 + mt * 16 + ln];
            uint byte = (w >> (quad * 8)) & 0xFFu;
            union { uint u[4]; bf16x8 v; } cv;
            #pragma unroll
            for (int p = 0; p < 4; ++p)
                cv.u[p] = (((byte >> (2 * p)) & 1u) ? 0x3F80u : 0u) |
                          (((byte >> (2 * p + 1)) & 1u) ? 0x3F800000u : 0u);
            afr[mt] = cv.v;
        }
        #pragma unroll
        for (int nt = 0; nt < 2; ++nt) {
            int n = wcol * 32 + nt * 16 + ln;
            bf16x8 bh = *(const bf16x8*)&bt[0][n][quad * 8];
            bf16x8 bm = *(const bf16x8*)&bt[1][n][quad * 8];
            bf16x8 bl = *(const bf16x8*)&bt[2][n][quad * 8];
            #pragma unroll
            for (int mt = 0; mt < 4; ++mt) {
                f32x4 a = acc[mt][nt];
                a = __builtin_amdgcn_mfma_f32_16x16x32_bf16(afr[mt], bh, a, 0, 0, 0);
                a = __builtin_amdgcn_mfma_f32_16x16x32_bf16(afr[mt], bm, a, 0, 0, 0);
                a = __builtin_amdgcn_mfma_f32_16x16x32_bf16(afr[mt], bl, a, 0, 0, 0);
                acc[mt][nt] = a;
            }
        }
        __syncthreads();
    }
    #pragma unroll
    for (int mt = 0; mt < 4; ++mt)
        #pragma unroll
        for (int nt = 0; nt < 2; ++nt)
            #pragma unroll
            for (int r = 0; r < 4; ++r) {
                int row = row0 + wrow * 64 + mt * 16 + quad * 4 + r;
                int col = col0 + wcol * 32 + nt * 16 + ln;
                size_t idx = (size_t)row * DD + col;
                X[idx] = X[idx] + acc[mt][nt][r];   // in-place: each idx owned by one thread
            }
}

// ---------------------------------------------------------------------------
// X = relu(bn(G)) @ W + bias;  acc (+)= X.  (proven)
// ---------------------------------------------------------------------------
__global__ __launch_bounds__(256, 2)
void gemm_bnrelu(const float* __restrict__ G, Ptrs4 Wp, Ptrs4 bp, Ptrs4 gbp,
                 const float* __restrict__ bns, const float* __restrict__ bnq,
                 float* __restrict__ Xout, float* __restrict__ accb, int first)
{
    const int b = blockIdx.z;
    const float* Wb = sel(Wp, b);
    const float* bb = sel(bp, b);
    const float* gb = sel(gbp, b);
    const float* Gb = G + (size_t)b * NN * DD;
    float* O = Xout + (size_t)b * NN * DD;
    float* Ab = accb + (size_t)b * NN * DD;
    const int row0 = blockIdx.y * 128, col0 = blockIdx.x * 64;
    const int tid = threadIdx.x;
    __shared__ float Asm[16][132];
    __shared__ float Bsm[16][68];
    __shared__ float scs[DD], shs[DD];
    {
        float mu = bns[b * DD + tid] * (1.0f / NN);
        float ms = bnq[b * DD + tid] * (1.0f / NN);
        float var = ms - mu * mu;
        float sc = gb[tid] / sqrtf(var + 1e-5f);
        scs[tid] = sc;
        shs[tid] = gb[DD + tid] - mu * sc;
    }
    __syncthreads();
    const int tr = (tid >> 4) << 3, tc = (tid & 15) << 2;
    const int m = tid & 127, kk = (tid >> 7) << 3;
    float acc[8][4] = {};
    for (int k0 = 0; k0 < DD; k0 += 16) {
        {
            const float* s1 = Gb + (size_t)(row0 + m) * DD + k0 + kk;
            float4 v0 = *(const float4*)s1, v1 = *(const float4*)(s1 + 4);
            float vv[8] = {v0.x, v0.y, v0.z, v0.w, v1.x, v1.y, v1.z, v1.w};
            #pragma unroll
            for (int i = 0; i < 8; ++i) {
                float v = fmaf(vv[i], scs[k0 + kk + i], shs[k0 + kk + i]);
                Asm[kk + i][m] = v > 0.f ? v : 0.f;
            }
        }
        {
            const int k = tid >> 4, n = (tid & 15) << 2;
            *(float4*)&Bsm[k][n] = *(const float4*)(Wb + (size_t)(k0 + k) * DD + col0 + n);
        }
        __syncthreads();
        #pragma unroll
        for (int k = 0; k < 16; ++k) {
            float a[8], bv[4];
            *(float4*)&a[0] = *(const float4*)&Asm[k][tr];
            *(float4*)&a[4] = *(const float4*)&Asm[k][tr + 4];
            *(float4*)&bv[0] = *(const float4*)&Bsm[k][tc];
            #pragma unroll
            for (int i = 0; i < 8; ++i)
                #pragma unroll
                for (int j = 0; j < 4; ++j)
                    acc[i][j] = fmaf(a[i], bv[j], acc[i][j]);
        }
        __syncthreads();
    }
    float bias4[4];
    *(float4*)bias4 = *(const float4*)(bb + col0 + tc);
    #pragma unroll
    for (int i = 0; i < 8; ++i) {
        size_t idx = (size_t)(row0 + tr + i) * DD + col0 + tc;
        float4 o;
        o.x = acc[i][0] + bias4[0]; o.y = acc[i][1] + bias4[1];
        o.z = acc[i][2] + bias4[2]; o.w = acc[i][3] + bias4[3];
        *(float4*)(O + idx) = o;
        if (first) {
            *(float4*)(Ab + idx) = o;
        } else {
            float4 p = *(const float4*)(Ab + idx);
            p.x += o.x; p.y += o.y; p.z += o.z; p.w += o.w;
            *(float4*)(Ab + idx) = p;
        }
    }
}

__global__ __launch_bounds__(256)
void mse_partial(const float* __restrict__ accb, double* __restrict__ msep)
{
    const int pair = blockIdx.x;
    const float* A_ = accb + (size_t)pair * NN * DD;
    const float* B_ = accb + (size_t)3 * NN * DD;
    const size_t total = (size_t)NN * DD;
    double s = 0.0;
    for (size_t i = (size_t)blockIdx.y * blockDim.x + threadIdx.x; i < total;
         i += (size_t)gridDim.y * blockDim.x) {
        float d = A_[i] - B_[i];
        s += (double)d * (double)d;
    }
    __shared__ double red[256];
    red[threadIdx.x] = s;
    __syncthreads();
    for (int st = 128; st > 0; st >>= 1) {
        if (threadIdx.x < st) red[threadIdx.x] += red[threadIdx.x + st];
        __syncthreads();
    }
    if (threadIdx.x == 0) atomicAdd(&msep[pair], red[0]);
}

__global__ void mse_final(const double* __restrict__ msep, float* __restrict__ out)
{
    int i = threadIdx.x;
    if (i < 3) out[i] = (float)(msep[i] / ((double)NN * DD) / 9.0);
}

static inline Ptrs4 mk4(const float* a, const float* b, const float* c, const float* d) {
    Ptrs4 p; p.p0 = a; p.p1 = b; p.p2 = c; p.p3 = d; return p;
}

extern "C" void kernel_launch(void* const* d_in, const int* in_sizes, int n_in,
                              void* d_out, int out_size, void* d_ws, size_t ws_size,
                              hipStream_t stream)
{
    (void)in_sizes; (void)n_in; (void)out_size; (void)ws_size;
    const float* adjW[3]  = {(const float*)d_in[4],  (const float*)d_in[9],  (const float*)d_in[14]};
    const float* adjb[3]  = {(const float*)d_in[5],  (const float*)d_in[10], (const float*)d_in[15]};
    const float* mlpW[3]  = {(const float*)d_in[6],  (const float*)d_in[11], (const float*)d_in[16]};
    const float* mlpb[3]  = {(const float*)d_in[7],  (const float*)d_in[12], (const float*)d_in[17]};
    const float* mlpbn[3] = {(const float*)d_in[8],  (const float*)d_in[13], (const float*)d_in[18]};

    // Workspace layout: identical proven footprint (~75 MB).
    char* ws = (char*)d_ws;
    double* msep  = (double*)ws;                 // [3]
    float* colsum = (float*)(ws + 64);           // [3][4][256]
    float* bnsum  = colsum + 3 * 4 * DD;
    float* bnsq   = bnsum  + 3 * 4 * DD;
    float* tvals  = bnsq   + 3 * 4 * DD;         // [4]
    const size_t tensN = (size_t)4 * NN * DD;
    float* Xbuf = (float*)(ws + 65536);
    float* Abuf = Xbuf + tensN;                  // h1 -> {Sh,Sm} -> g
    float* Bbuf = Abuf + tensN;                  // h2 -> {Sl}
    float* accb = Bbuf + tensN;
    uint8_t* mask = (uint8_t*)(accb + tensN);    // [4][N][N/8] = 8 MB
    // bf16 split views (time-multiplexed over Abuf/Bbuf)
    ushort_t* Sh = (ushort_t*)Abuf;              // [4][D][N] = 8.4 MB
    ushort_t* Sm = Sh + tensN;                   // second half of Abuf
    ushort_t* Sl = (ushort_t*)Bbuf;              // first half of Bbuf

    hipMemsetAsync(ws, 0, 64 + 3 * 3 * 4 * DD * sizeof(float), stream);
    for (int b = 0; b < 4; ++b)
        hipMemcpyAsync(Xbuf + (size_t)b * NN * DD, d_in[b], (size_t)NN * DD * sizeof(float),
                       hipMemcpyDeviceToDevice, stream);

    dim3 gS(4, 32, 4);      // fp32 GEMMs / masked_mfma
    dim3 gA(528, 1, 4);     // adj tiles, compact upper-tri
    dim3 gT(64, 4, 4);      // tsplit_x
    dim3 blk(256);

    for (int l = 0; l < NL; ++l) {
        float* cs_l = colsum + l * 4 * DD;
        float* bs_l = bnsum + l * 4 * DD;
        float* bq_l = bnsq  + l * 4 * DD;
        #define MK(arr, off) mk4(arr[0] + (off), arr[1] + (off), arr[2] + (off), arr[1] + (off))
        // h1 = elu(X @ aW0 + ab0)  -> Abuf
        gemm_small<0><<<gS, blk, 0, stream>>>(Xbuf, MK(adjW, 0), MK(adjb, 0), Abuf, nullptr, nullptr);
        // h2 = elu(h1 @ aW1 + ab1) + colsum  -> Bbuf
        gemm_small<1><<<gS, blk, 0, stream>>>(Abuf, MK(adjW, (size_t)DD * DD), MK(adjb, DD),
                                              Bbuf, cs_l, nullptr);
        thresh_k<<<4, blk, 0, stream>>>(cs_l, tvals);
        // mask = (h2 h2^T > mean), symmetric-halved, compact grid
        adj_mfma_s<<<gA, blk, 0, stream>>>(Bbuf, tvals, mask);
        // splits of X^T (h1, h2 dead) -> Sh,Sm (Abuf), Sl (Bbuf)
        tsplit_x<<<gT, blk, 0, stream>>>(Xbuf, Sh, Sm, Sl);
        // X = X + M @ X   (in-place Xbuf)
        masked_mfma<<<gS, blk, 0, stream>>>(Xbuf, Sh, Sm, Sl, mask);
        const size_t w0 = (size_t)l * 2 * DD * DD, b0 = (size_t)l * 2 * DD;
        // g = X' @ mW0 + mb0 + BN stats  -> Abuf (splits dead)
        gemm_small<2><<<gS, blk, 0, stream>>>(Xbuf, MK(mlpW, w0), MK(mlpb, b0), Abuf, bs_l, bq_l);
        // X = relu(bn(g)) @ mW1 + mb1;  acc (+)= X  -> Xbuf
        gemm_bnrelu<<<gS, blk, 0, stream>>>(Abuf, MK(mlpW, w0 + (size_t)DD * DD), MK(mlpb, b0 + DD),
                                            MK(mlpbn, b0), bs_l, bq_l, Xbuf, accb, (l == 0) ? 1 : 0);
        #undef MK
    }
    mse_partial<<<dim3(3, 64), blk, 0, stream>>>(accb, msep);
    mse_final<<<1, 64, 0, stream>>>(msep, (float*)d_out);
}

// Round 9
// 1422.650 us; speedup vs baseline: 1.1362x; 1.0107x over previous
//
#include <hip/hip_runtime.h>
#include <hip/hip_bf16.h>
#include <stdint.h>

#define NN 4096
#define DD 256
#define NL 3
typedef unsigned int uint;
typedef unsigned short ushort_t;

typedef float f32x4 __attribute__((ext_vector_type(4)));
typedef short bf16x8 __attribute__((ext_vector_type(8)));

struct Ptrs4 { const float* p0; const float* p1; const float* p2; const float* p3; };
__device__ __forceinline__ const float* sel(const Ptrs4& p, int b) {
    return b == 0 ? p.p0 : b == 1 ? p.p1 : b == 2 ? p.p2 : p.p3;
}

// packed bf16 pair (RNE), low half = a, high half = b
__device__ __forceinline__ uint pkbf2(float a, float b) {
    __hip_bfloat162 t = __float22bfloat162_rn(float2{a, b});
    union { __hip_bfloat162 h; uint u; } c; c.h = t; return c.u;
}
// exact 3-way split of a pair: x = h + m + l + r, |r| <= ~2^-27 |x|
__device__ __forceinline__ void split3_pk(float a, float b, uint& h, uint& m, uint& l) {
    h = pkbf2(a, b);
    float ha = __uint_as_float(h << 16), hb = __uint_as_float(h & 0xFFFF0000u);
    float ra = a - ha, rb = b - hb;
    m = pkbf2(ra, rb);
    float ma = __uint_as_float(m << 16), mb = __uint_as_float(m & 0xFFFF0000u);
    l = pkbf2(ra - ma, rb - mb);
}

// ---------------------------------------------------------------------------
// fp32 GEMM (proven): Out = act(X @ W + b).
// MODE 0: elu; MODE 1: elu + colsum; MODE 2: linear + BN stats.
// R9: occupancy cap raised 2 -> 4 blocks/CU (44 VGPR, 12.8 KB LDS permit it).
// ---------------------------------------------------------------------------
template<int MODE>
__global__ __launch_bounds__(256, 4)
void gemm_small(const float* __restrict__ Xin, Ptrs4 Wp, Ptrs4 bp,
                float* __restrict__ Out, float* __restrict__ cs, float* __restrict__ csq)
{
    const int b = blockIdx.z;
    const float* Wb = sel(Wp, b);
    const float* bb = sel(bp, b);
    const float* X = Xin + (size_t)b * NN * DD;
    float* O = Out + (size_t)b * NN * DD;
    const int row0 = blockIdx.y * 128, col0 = blockIdx.x * 64;
    const int tid = threadIdx.x;
    __shared__ float Asm[16][132];
    __shared__ float Bsm[16][68];
    const int tr = (tid >> 4) << 3, tc = (tid & 15) << 2;
    const int m = tid & 127, kk = (tid >> 7) << 3;
    float acc[8][4] = {};
    for (int k0 = 0; k0 < DD; k0 += 16) {
        {
            const float* s1 = X + (size_t)(row0 + m) * DD + k0 + kk;
            float4 v0 = *(const float4*)s1, v1 = *(const float4*)(s1 + 4);
            Asm[kk+0][m]=v0.x; Asm[kk+1][m]=v0.y; Asm[kk+2][m]=v0.z; Asm[kk+3][m]=v0.w;
            Asm[kk+4][m]=v1.x; Asm[kk+5][m]=v1.y; Asm[kk+6][m]=v1.z; Asm[kk+7][m]=v1.w;
        }
        {
            const int k = tid >> 4, n = (tid & 15) << 2;
            *(float4*)&Bsm[k][n] = *(const float4*)(Wb + (size_t)(k0 + k) * DD + col0 + n);
        }
        __syncthreads();
        #pragma unroll
        for (int k = 0; k < 16; ++k) {
            float a[8], bv[4];
            *(float4*)&a[0] = *(const float4*)&Asm[k][tr];
            *(float4*)&a[4] = *(const float4*)&Asm[k][tr + 4];
            *(float4*)&bv[0] = *(const float4*)&Bsm[k][tc];
            #pragma unroll
            for (int i = 0; i < 8; ++i)
                #pragma unroll
                for (int j = 0; j < 4; ++j)
                    acc[i][j] = fmaf(a[i], bv[j], acc[i][j]);
        }
        __syncthreads();
    }
    float bias4[4];
    *(float4*)bias4 = *(const float4*)(bb + col0 + tc);
    float s4[4] = {0.f,0.f,0.f,0.f}, q4[4] = {0.f,0.f,0.f,0.f};
    #pragma unroll
    for (int i = 0; i < 8; ++i) {
        float ov[4];
        #pragma unroll
        for (int j = 0; j < 4; ++j) {
            float v = acc[i][j] + bias4[j];
            if (MODE == 0 || MODE == 1) v = (v > 0.f) ? v : (expf(v) - 1.f);
            ov[j] = v;
            if (MODE == 1) s4[j] += v;
            if (MODE == 2) { s4[j] += v; q4[j] += v * v; }
        }
        float4 o; o.x = ov[0]; o.y = ov[1]; o.z = ov[2]; o.w = ov[3];
        *(float4*)(O + (size_t)(row0 + tr + i) * DD + col0 + tc) = o;
    }
    if (MODE == 1 || MODE == 2) {
        __syncthreads();
        const int rg = tid >> 4;
        #pragma unroll
        for (int j = 0; j < 4; ++j) {
            Asm[rg][tc + j] = s4[j];
            if (MODE == 2) Bsm[rg][tc + j] = q4[j];
        }
        __syncthreads();
        if (tid < 64) {
            float s = 0.f, q = 0.f;
            #pragma unroll
            for (int r = 0; r < 16; ++r) { s += Asm[r][tid]; if (MODE == 2) q += Bsm[r][tid]; }
            atomicAdd(&cs[b * DD + col0 + tid], s);
            if (MODE == 2) atomicAdd(&csq[b * DD + col0 + tid], q);
        }
    }
}

// threshold per branch: t = ||colsum||^2 / N^2
__global__ void thresh_k(const float* __restrict__ cs, float* __restrict__ tvals)
{
    const int b = blockIdx.x, t = threadIdx.x;
    __shared__ float red[256];
    float v = cs[b * DD + t];
    red[t] = v * v;
    __syncthreads();
    for (int s = 128; s > 0; s >>= 1) { if (t < s) red[t] += red[t + s]; __syncthreads(); }
    if (t == 0) tvals[b] = red[0] * (1.0f / 16777216.0f);
}

// ---------------------------------------------------------------------------
// transpose + exact 3-split: X[b][n][d] fp32 -> S{h,m,l}[b][d][j=n] bf16.
// j-contiguous layout = MFMA k-order for masked_mfma's B operand.  (proven)
// ---------------------------------------------------------------------------
__global__ __launch_bounds__(256)
void tsplit_x(const float* __restrict__ Xin, ushort_t* __restrict__ Sh,
              ushort_t* __restrict__ Sm, ushort_t* __restrict__ Sl)
{
    const int b = blockIdx.z;
    const int n0 = blockIdx.x * 64, d0 = blockIdx.y * 64;
    const float* X = Xin + (size_t)b * NN * DD;
    __shared__ float ls[64][65];
    const int tid = threadIdx.x;
    #pragma unroll
    for (int i = 0; i < 4; ++i) {
        int u = (i << 8) + tid;
        int r = u >> 4, c4 = (u & 15) << 2;   // r = n-row, c4 = d offset
        float4 v = *(const float4*)(X + (size_t)(n0 + r) * DD + d0 + c4);
        ls[r][c4] = v.x; ls[r][c4+1] = v.y; ls[r][c4+2] = v.z; ls[r][c4+3] = v.w;
    }
    __syncthreads();
    const int d = tid >> 2, seg = (tid & 3) << 4;   // 16 n-values per thread
    uint ph[8], pm[8], pl[8];
    #pragma unroll
    for (int jj = 0; jj < 8; ++jj) {
        float a = ls[seg + 2 * jj][d];
        float c = ls[seg + 2 * jj + 1][d];
        split3_pk(a, c, ph[jj], pm[jj], pl[jj]);
    }
    size_t idx = ((size_t)(b * DD + d0 + d)) * NN + n0 + seg;   // ushort units
    *(uint4*)(Sh + idx)     = *(uint4*)&ph[0];
    *(uint4*)(Sh + idx + 8) = *(uint4*)&ph[4];
    *(uint4*)(Sm + idx)     = *(uint4*)&pm[0];
    *(uint4*)(Sm + idx + 8) = *(uint4*)&pm[4];
    *(uint4*)(Sl + idx)     = *(uint4*)&pl[0];
    *(uint4*)(Sl + idx + 8) = *(uint4*)&pl[4];
}

// ---------------------------------------------------------------------------
// adj via MFMA, symmetric-halved with compact triangular grid (528 blocks
// per branch) and 51 KB LDS -> 3 blocks/CU. Split once per LDS tile;
// 6 products; bits via ballot; mirror tile from the same accumulators.
// ---------------------------------------------------------------------------
__global__ __launch_bounds__(256, 3)
void adj_mfma_s(const float* __restrict__ H, const float* __restrict__ tvals,
                uint8_t* __restrict__ mask)
{
    // decode linear triangular index -> (by, bx), bx >= by, row-major
    int t = blockIdx.x;
    int by = 0, rem = 32;
    while (t >= rem) { t -= rem; rem--; by++; }
    const int bx = by + t;
    const int b = blockIdx.z;
    const int row0 = by * 128, col0 = bx * 128;
    const int tid = threadIdx.x;
    const int wave = tid >> 6, ln = tid & 15, quad = (tid >> 4) & 3;
    const int wrow = wave >> 1, wcol = wave & 1;
    const float* Hb = H + (size_t)b * NN * DD;
    uint8_t* Mb = mask + (size_t)b * NN * (NN / 8);
    __shared__ ushort_t hs[2][3][128][34];   // [side][lvl][row][32k+pad], 51.0 KB

    f32x4 acc[4][4] = {};
    for (int k0 = 0; k0 < DD; k0 += 32) {
        #pragma unroll
        for (int i = 0; i < 8; ++i) {
            int f = (i << 8) + tid;
            int sr = f >> 3;                 // (side,row)
            int side = sr >> 7, r = sr & 127, part = f & 7;   // part = 4-k group
            int grow = (side ? col0 : row0) + r;
            float4 v = *(const float4*)(Hb + (size_t)grow * DD + k0 + part * 4);
            uint h0, m0, l0, h1, m1, l1;
            split3_pk(v.x, v.y, h0, m0, l0);
            split3_pk(v.z, v.w, h1, m1, l1);
            uint2 ph; ph.x = h0; ph.y = h1;
            uint2 pm; pm.x = m0; pm.y = m1;
            uint2 pl; pl.x = l0; pl.y = l1;
            *(uint2*)&hs[side][0][r][part * 4] = ph;
            *(uint2*)&hs[side][1][r][part * 4] = pm;
            *(uint2*)&hs[side][2][r][part * 4] = pl;
        }
        __syncthreads();
        bf16x8 af[4][3];
        #pragma unroll
        for (int mt = 0; mt < 4; ++mt)
            #pragma unroll
            for (int lvl = 0; lvl < 3; ++lvl)
                af[mt][lvl] = *(const bf16x8*)&hs[0][lvl][wrow * 64 + mt * 16 + ln][quad * 8];
        #pragma unroll
        for (int nt = 0; nt < 4; ++nt) {
            int n = wcol * 64 + nt * 16 + ln;
            bf16x8 bh = *(const bf16x8*)&hs[1][0][n][quad * 8];
            bf16x8 bm = *(const bf16x8*)&hs[1][1][n][quad * 8];
            bf16x8 bl = *(const bf16x8*)&hs[1][2][n][quad * 8];
            #pragma unroll
            for (int mt = 0; mt < 4; ++mt) {
                f32x4 a = acc[mt][nt];
                a = __builtin_amdgcn_mfma_f32_16x16x32_bf16(af[mt][0], bh, a, 0, 0, 0);
                a = __builtin_amdgcn_mfma_f32_16x16x32_bf16(af[mt][0], bm, a, 0, 0, 0);
                a = __builtin_amdgcn_mfma_f32_16x16x32_bf16(af[mt][1], bh, a, 0, 0, 0);
                a = __builtin_amdgcn_mfma_f32_16x16x32_bf16(af[mt][0], bl, a, 0, 0, 0);
                a = __builtin_amdgcn_mfma_f32_16x16x32_bf16(af[mt][2], bh, a, 0, 0, 0);
                a = __builtin_amdgcn_mfma_f32_16x16x32_bf16(af[mt][1], bm, a, 0, 0, 0);
                acc[mt][nt] = a;
            }
        }
        __syncthreads();
    }
    const float t2 = tvals[b];
    #pragma unroll
    for (int mt = 0; mt < 4; ++mt)
        #pragma unroll
        for (int nt = 0; nt < 4; ++nt) {
            bool p0 = acc[mt][nt][0] > t2, p1 = acc[mt][nt][1] > t2;
            bool p2 = acc[mt][nt][2] > t2, p3 = acc[mt][nt][3] > t2;
            // --- normal tile: bits across lanes (cols) via ballot ---
            unsigned long long bal[4];
            bal[0] = __ballot(p0); bal[1] = __ballot(p1);
            bal[2] = __ballot(p2); bal[3] = __ballot(p3);
            if ((tid & 63) < 16) {
                int q = ln >> 2, rsel = ln & 3;
                unsigned long long bv = rsel == 0 ? bal[0] : rsel == 1 ? bal[1]
                                       : rsel == 2 ? bal[2] : bal[3];
                ushort_t u16 = (ushort_t)((bv >> (q * 16)) & 0xFFFFull);
                int row = row0 + wrow * 64 + mt * 16 + ln;
                int colb = (col0 + wcol * 64 + nt * 16) >> 3;
                *(ushort_t*)(Mb + (size_t)row * (NN / 8) + colb) = u16;
            }
            // --- mirror tile: bits across rows, assembled from quad pairs ---
            uint nib = (p0 ? 1u : 0u) | (p1 ? 2u : 0u) | (p2 ? 4u : 0u) | (p3 ? 8u : 0u);
            uint other = (uint)__shfl_xor((int)nib, 16);   // partner quad (q^1)
            if ((quad & 1) == 0) {
                uint byt = nib | (other << 4);
                int rowm = col0 + wcol * 64 + nt * 16 + ln;
                int colbm = ((row0 + wrow * 64 + mt * 16) >> 3) + (quad >> 1);
                Mb[(size_t)rowm * (NN / 8) + colbm] = (uint8_t)byt;
            }
        }
}

// ---------------------------------------------------------------------------
// X' = X + M @ X via MFMA, IN-PLACE into X. A = mask bits -> exact {0,1}
// bf16; B staged from precomputed global bf16 splits [lvl][d][j].
// R9: occupancy cap raised 3 -> 6 blocks/CU (48 VGPR, 16 KB LDS permit it).
// ---------------------------------------------------------------------------
__global__ __launch_bounds__(256, 6)
void masked_mfma(float* __restrict__ Xio, const ushort_t* __restrict__ Sh,
                 const ushort_t* __restrict__ Sm, const ushort_t* __restrict__ Sl,
                 const uint8_t* __restrict__ mask)
{
    const int b = blockIdx.z;
    const int row0 = blockIdx.y * 128, col0 = blockIdx.x * 64;
    const int tid = threadIdx.x;
    const int wave = tid >> 6, ln = tid & 15, quad = (tid >> 4) & 3;
    const int wrow = wave >> 1, wcol = wave & 1;
    float* X = Xio + (size_t)b * NN * DD;
    const size_t sb = (size_t)b * DD * NN;
    const ushort_t* Ss[3] = { Sh + sb, Sm + sb, Sl + sb };
    const uint* Mw = (const uint*)(mask + (size_t)b * NN * (NN / 8));
    __shared__ ushort_t bt[3][64][40];   // [lvl][col][32 j + pad], 15.4 KB
    __shared__ uint msk[128];

    f32x4 acc[4][2] = {};
    const int scol = tid >> 2, spart = tid & 3;
    for (int j0 = 0; j0 < NN; j0 += 32) {
        #pragma unroll
        for (int lvl = 0; lvl < 3; ++lvl) {
            uint4 v = *(const uint4*)(Ss[lvl] + (size_t)(col0 + scol) * NN + j0 + spart * 8);
            *(uint4*)&bt[lvl][scol][spart * 8] = v;
        }
        if (tid < 128) msk[tid] = Mw[(size_t)(row0 + tid) * 128 + (j0 >> 5)];
        __syncthreads();
        bf16x8 afr[4];
        #pragma unroll
        for (int mt = 0; mt < 4; ++mt) {
            uint w = msk[wrow * 64 + mt * 16 + ln];
            uint byte = (w >> (quad * 8)) & 0xFFu;
            union { uint u[4]; bf16x8 v; } cv;
            #pragma unroll
            for (int p = 0; p < 4; ++p)
                cv.u[p] = (((byte >> (2 * p)) & 1u) ? 0x3F80u : 0u) |
                          (((byte >> (2 * p + 1)) & 1u) ? 0x3F800000u : 0u);
            afr[mt] = cv.v;
        }
        #pragma unroll
        for (int nt = 0; nt < 2; ++nt) {
            int n = wcol * 32 + nt * 16 + ln;
            bf16x8 bh = *(const bf16x8*)&bt[0][n][quad * 8];
            bf16x8 bm = *(const bf16x8*)&bt[1][n][quad * 8];
            bf16x8 bl = *(const bf16x8*)&bt[2][n][quad * 8];
            #pragma unroll
            for (int mt = 0; mt < 4; ++mt) {
                f32x4 a = acc[mt][nt];
                a = __builtin_amdgcn_mfma_f32_16x16x32_bf16(afr[mt], bh, a, 0, 0, 0);
                a = __builtin_amdgcn_mfma_f32_16x16x32_bf16(afr[mt], bm, a, 0, 0, 0);
                a = __builtin_amdgcn_mfma_f32_16x16x32_bf16(afr[mt], bl, a, 0, 0, 0);
                acc[mt][nt] = a;
            }
        }
        __syncthreads();
    }
    #pragma unroll
    for (int mt = 0; mt < 4; ++mt)
        #pragma unroll
        for (int nt = 0; nt < 2; ++nt)
            #pragma unroll
            for (int r = 0; r < 4; ++r) {
                int row = row0 + wrow * 64 + mt * 16 + quad * 4 + r;
                int col = col0 + wcol * 32 + nt * 16 + ln;
                size_t idx = (size_t)row * DD + col;
                X[idx] = X[idx] + acc[mt][nt][r];   // in-place: each idx owned by one thread
            }
}

// ---------------------------------------------------------------------------
// X = relu(bn(G)) @ W + bias;  acc (+)= X.
// R9: occupancy cap raised 2 -> 4 blocks/CU.
// ---------------------------------------------------------------------------
__global__ __launch_bounds__(256, 4)
void gemm_bnrelu(const float* __restrict__ G, Ptrs4 Wp, Ptrs4 bp, Ptrs4 gbp,
                 const float* __restrict__ bns, const float* __restrict__ bnq,
                 float* __restrict__ Xout, float* __restrict__ accb, int first)
{
    const int b = blockIdx.z;
    const float* Wb = sel(Wp, b);
    const float* bb = sel(bp, b);
    const float* gb = sel(gbp, b);
    const float* Gb = G + (size_t)b * NN * DD;
    float* O = Xout + (size_t)b * NN * DD;
    float* Ab = accb + (size_t)b * NN * DD;
    const int row0 = blockIdx.y * 128, col0 = blockIdx.x * 64;
    const int tid = threadIdx.x;
    __shared__ float Asm[16][132];
    __shared__ float Bsm[16][68];
    __shared__ float scs[DD], shs[DD];
    {
        float mu = bns[b * DD + tid] * (1.0f / NN);
        float ms = bnq[b * DD + tid] * (1.0f / NN);
        float var = ms - mu * mu;
        float sc = gb[tid] / sqrtf(var + 1e-5f);
        scs[tid] = sc;
        shs[tid] = gb[DD + tid] - mu * sc;
    }
    __syncthreads();
    const int tr = (tid >> 4) << 3, tc = (tid & 15) << 2;
    const int m = tid & 127, kk = (tid >> 7) << 3;
    float acc[8][4] = {};
    for (int k0 = 0; k0 < DD; k0 += 16) {
        {
            const float* s1 = Gb + (size_t)(row0 + m) * DD + k0 + kk;
            float4 v0 = *(const float4*)s1, v1 = *(const float4*)(s1 + 4);
            float vv[8] = {v0.x, v0.y, v0.z, v0.w, v1.x, v1.y, v1.z, v1.w};
            #pragma unroll
            for (int i = 0; i < 8; ++i) {
                float v = fmaf(vv[i], scs[k0 + kk + i], shs[k0 + kk + i]);
                Asm[kk + i][m] = v > 0.f ? v : 0.f;
            }
        }
        {
            const int k = tid >> 4, n = (tid & 15) << 2;
            *(float4*)&Bsm[k][n] = *(const float4*)(Wb + (size_t)(k0 + k) * DD + col0 + n);
        }
        __syncthreads();
        #pragma unroll
        for (int k = 0; k < 16; ++k) {
            float a[8], bv[4];
            *(float4*)&a[0] = *(const float4*)&Asm[k][tr];
            *(float4*)&a[4] = *(const float4*)&Asm[k][tr + 4];
            *(float4*)&bv[0] = *(const float4*)&Bsm[k][tc];
            #pragma unroll
            for (int i = 0; i < 8; ++i)
                #pragma unroll
                for (int j = 0; j < 4; ++j)
                    acc[i][j] = fmaf(a[i], bv[j], acc[i][j]);
        }
        __syncthreads();
    }
    float bias4[4];
    *(float4*)bias4 = *(const float4*)(bb + col0 + tc);
    #pragma unroll
    for (int i = 0; i < 8; ++i) {
        size_t idx = (size_t)(row0 + tr + i) * DD + col0 + tc;
        float4 o;
        o.x = acc[i][0] + bias4[0]; o.y = acc[i][1] + bias4[1];
        o.z = acc[i][2] + bias4[2]; o.w = acc[i][3] + bias4[3];
        *(float4*)(O + idx) = o;
        if (first) {
            *(float4*)(Ab + idx) = o;
        } else {
            float4 p = *(const float4*)(Ab + idx);
            p.x += o.x; p.y += o.y; p.z += o.z; p.w += o.w;
            *(float4*)(Ab + idx) = p;
        }
    }
}

__global__ __launch_bounds__(256)
void mse_partial(const float* __restrict__ accb, double* __restrict__ msep)
{
    const int pair = blockIdx.x;
    const float* A_ = accb + (size_t)pair * NN * DD;
    const float* B_ = accb + (size_t)3 * NN * DD;
    const size_t total = (size_t)NN * DD;
    double s = 0.0;
    for (size_t i = (size_t)blockIdx.y * blockDim.x + threadIdx.x; i < total;
         i += (size_t)gridDim.y * blockDim.x) {
        float d = A_[i] - B_[i];
        s += (double)d * (double)d;
    }
    __shared__ double red[256];
    red[threadIdx.x] = s;
    __syncthreads();
    for (int st = 128; st > 0; st >>= 1) {
        if (threadIdx.x < st) red[threadIdx.x] += red[threadIdx.x + st];
        __syncthreads();
    }
    if (threadIdx.x == 0) atomicAdd(&msep[pair], red[0]);
}

__global__ void mse_final(const double* __restrict__ msep, float* __restrict__ out)
{
    int i = threadIdx.x;
    if (i < 3) out[i] = (float)(msep[i] / ((double)NN * DD) / 9.0);
}

static inline Ptrs4 mk4(const float* a, const float* b, const float* c, const float* d) {
    Ptrs4 p; p.p0 = a; p.p1 = b; p.p2 = c; p.p3 = d; return p;
}

extern "C" void kernel_launch(void* const* d_in, const int* in_sizes, int n_in,
                              void* d_out, int out_size, void* d_ws, size_t ws_size,
                              hipStream_t stream)
{
    (void)in_sizes; (void)n_in; (void)out_size; (void)ws_size;
    const float* adjW[3]  = {(const float*)d_in[4],  (const float*)d_in[9],  (const float*)d_in[14]};
    const float* adjb[3]  = {(const float*)d_in[5],  (const float*)d_in[10], (const float*)d_in[15]};
    const float* mlpW[3]  = {(const float*)d_in[6],  (const float*)d_in[11], (const float*)d_in[16]};
    const float* mlpb[3]  = {(const float*)d_in[7],  (const float*)d_in[12], (const float*)d_in[17]};
    const float* mlpbn[3] = {(const float*)d_in[8],  (const float*)d_in[13], (const float*)d_in[18]};

    // Workspace layout: identical proven footprint (~75 MB).
    char* ws = (char*)d_ws;
    double* msep  = (double*)ws;                 // [3]
    float* colsum = (float*)(ws + 64);           // [3][4][256]
    float* bnsum  = colsum + 3 * 4 * DD;
    float* bnsq   = bnsum  + 3 * 4 * DD;
    float* tvals  = bnsq   + 3 * 4 * DD;         // [4]
    const size_t tensN = (size_t)4 * NN * DD;
    float* Xbuf = (float*)(ws + 65536);
    float* Abuf = Xbuf + tensN;                  // h1 -> {Sh,Sm} -> g
    float* Bbuf = Abuf + tensN;                  // h2 -> {Sl}
    float* accb = Bbuf + tensN;
    uint8_t* mask = (uint8_t*)(accb + tensN);    // [4][N][N/8] = 8 MB
    // bf16 split views (time-multiplexed over Abuf/Bbuf)
    ushort_t* Sh = (ushort_t*)Abuf;              // [4][D][N] = 8.4 MB
    ushort_t* Sm = Sh + tensN;                   // second half of Abuf
    ushort_t* Sl = (ushort_t*)Bbuf;              // first half of Bbuf

    hipMemsetAsync(ws, 0, 64 + 3 * 3 * 4 * DD * sizeof(float), stream);
    for (int b = 0; b < 4; ++b)
        hipMemcpyAsync(Xbuf + (size_t)b * NN * DD, d_in[b], (size_t)NN * DD * sizeof(float),
                       hipMemcpyDeviceToDevice, stream);

    dim3 gS(4, 32, 4);      // fp32 GEMMs / masked_mfma
    dim3 gA(528, 1, 4);     // adj tiles, compact upper-tri
    dim3 gT(64, 4, 4);      // tsplit_x
    dim3 blk(256);

    for (int l = 0; l < NL; ++l) {
        float* cs_l = colsum + l * 4 * DD;
        float* bs_l = bnsum + l * 4 * DD;
        float* bq_l = bnsq  + l * 4 * DD;
        #define MK(arr, off) mk4(arr[0] + (off), arr[1] + (off), arr[2] + (off), arr[1] + (off))
        // h1 = elu(X @ aW0 + ab0)  -> Abuf
        gemm_small<0><<<gS, blk, 0, stream>>>(Xbuf, MK(adjW, 0), MK(adjb, 0), Abuf, nullptr, nullptr);
        // h2 = elu(h1 @ aW1 + ab1) + colsum  -> Bbuf
        gemm_small<1><<<gS, blk, 0, stream>>>(Abuf, MK(adjW, (size_t)DD * DD), MK(adjb, DD),
                                              Bbuf, cs_l, nullptr);
        thresh_k<<<4, blk, 0, stream>>>(cs_l, tvals);
        // mask = (h2 h2^T > mean), symmetric-halved, compact grid
        adj_mfma_s<<<gA, blk, 0, stream>>>(Bbuf, tvals, mask);
        // splits of X^T (h1, h2 dead) -> Sh,Sm (Abuf), Sl (Bbuf)
        tsplit_x<<<gT, blk, 0, stream>>>(Xbuf, Sh, Sm, Sl);
        // X = X + M @ X   (in-place Xbuf)
        masked_mfma<<<gS, blk, 0, stream>>>(Xbuf, Sh, Sm, Sl, mask);
        const size_t w0 = (size_t)l * 2 * DD * DD, b0 = (size_t)l * 2 * DD;
        // g = X' @ mW0 + mb0 + BN stats  -> Abuf (splits dead)
        gemm_small<2><<<gS, blk, 0, stream>>>(Xbuf, MK(mlpW, w0), MK(mlpb, b0), Abuf, bs_l, bq_l);
        // X = relu(bn(g)) @ mW1 + mb1;  acc (+)= X  -> Xbuf
        gemm_bnrelu<<<gS, blk, 0, stream>>>(Abuf, MK(mlpW, w0 + (size_t)DD * DD), MK(mlpb, b0 + DD),
                                            MK(mlpbn, b0), bs_l, bq_l, Xbuf, accb, (l == 0) ? 1 : 0);
        #undef MK
    }
    mse_partial<<<dim3(3, 64), blk, 0, stream>>>(accb, msep);
    mse_final<<<1, 64, 0, stream>>>(msep, (float*)d_out);
}